// Round 4
// baseline (239.675 us; speedup 1.0000x reference)
//
#include <hip/hip_runtime.h>

#define B 8
#define N 2048
#define FIN 10
#define D 128
#define ALPHA 0.02f
#define LOG2E 1.44269504088896340736f
#define BR 32     // rows per block, k_proj
#define TI 32     // rows per block, k_attn
#define JC 128    // j-chunk, k_attn
#define NBLK_ATTN ((N / TI) * B)   // 512

typedef short bf8 __attribute__((ext_vector_type(8)));   // 8 bf16 in 4 VGPRs
typedef short s4v __attribute__((ext_vector_type(4)));
typedef float f32x4 __attribute__((ext_vector_type(4)));

__device__ __forceinline__ float lrelu(float x) { return x >= 0.f ? x : ALPHA * x; }

// f32 -> bf16 RNE (used for weights/Wh only)
__device__ __forceinline__ short f2b(float f) {
    unsigned u = __float_as_uint(f);
    return (short)((u + 0x7fffu + ((u >> 16) & 1u)) >> 16);
}

// exp2 via v_exp_f32
__device__ __forceinline__ float fexp2(float x) {
#if __has_builtin(__builtin_amdgcn_exp2f)
    return __builtin_amdgcn_exp2f(x);
#else
    return exp2f(x);
#endif
}

// pack two f32 -> two bf16 (truncation) in one v_perm
__device__ __forceinline__ unsigned pack2(float lo, float hi) {
#if __has_builtin(__builtin_amdgcn_perm)
    return __builtin_amdgcn_perm(__float_as_uint(hi), __float_as_uint(lo), 0x07060302u);
#else
    return (__float_as_uint(hi) & 0xFFFF0000u) | (__float_as_uint(lo) >> 16);
#endif
}

__device__ __forceinline__ unsigned enc_key(float v) {
    unsigned b = __float_as_uint(v);
    return (b & 0x80000000u) ? ~b : (b | 0x80000000u);
}
__device__ __forceinline__ float dec_key(unsigned k) {
    unsigned b = (k & 0x80000000u) ? (k & 0x7fffffffu) : ~k;
    return __uint_as_float(b);
}

// ---------------------------------------------------------------------------
// k_prep: one-time Wg fp32->bf16 (RNE) + zero-init pooled/cnt.
// Grid 16 x 256 threads; thread g handles 4 elements of Wg (16384 total).
// ---------------------------------------------------------------------------
__global__ __launch_bounds__(256) void k_prep(
    const float* __restrict__ Wg, unsigned short* __restrict__ Wgb,
    unsigned* __restrict__ pooled, unsigned* __restrict__ cnt)
{
    const int g = blockIdx.x * 256 + threadIdx.x;    // 0..4095
    float4 f = *(const float4*)&Wg[g * 4];
    s4v v;
    v[0] = f2b(f.x); v[1] = f2b(f.y); v[2] = f2b(f.z); v[3] = f2b(f.w);
    *(s4v*)&Wgb[g * 4] = v;
    if (g < B * D) pooled[g] = 0u;
    if (g == B * D) *cnt = 0u;
}

// ---------------------------------------------------------------------------
// k_proj: x = lrelu(LN(h@W1^T+b1)) [bf16] ; Wh = x@Wg^T+bg via MFMA (fp32 acc);
// emits WhT bf16 [d][j] + e1,e2 (pre-scaled by log2(e)) fp32.
// Block = 32 rows, 256 threads (4 waves). Grid = B*N/32 = 512.
// ---------------------------------------------------------------------------
__global__ __launch_bounds__(256) void k_proj(
    const float* __restrict__ h, const float* __restrict__ W1, const float* __restrict__ b1,
    const unsigned short* __restrict__ Wgb, const float* __restrict__ bg,
    const float* __restrict__ a1, const float* __restrict__ a2,
    unsigned short* __restrict__ WhT, float* __restrict__ e1g, float* __restrict__ e2g)
{
    __shared__ __align__(16) short xep_lds[32 * 136];
    __shared__ __align__(16) short wg_lds[D * 136];
    __shared__ float W1_lds[D * 11];
    __shared__ float h_lds[BR * FIN];
    __shared__ float ep1[2][BR], ep2[2][BR];

    const int t = threadIdx.x;
    const int r0 = blockIdx.x * BR;
    const int bb = r0 >> 11;
    const int jloc = r0 & (N - 1);

    for (int idx = t; idx < D * FIN; idx += 256)
        W1_lds[(idx / FIN) * 11 + (idx % FIN)] = W1[idx];
    for (int idx = t; idx < BR * FIN; idx += 256)
        h_lds[idx] = h[(size_t)r0 * FIN + idx];
    __syncthreads();

    // stage pre-converted Wg bf16 -> LDS (straight copy, coalesced)
    {
        const int dr = t >> 4;
        const int j8 = t & 15;
        #pragma unroll
        for (int pass = 0; pass < 8; pass++) {
            int dd = pass * 16 + dr;
            *(bf8*)&wg_lds[dd * 136 + j8 * 8] = *(const bf8*)&Wgb[dd * D + j8 * 8];
        }
    }

    // phase 1: fc1 + LN + lrelu, one row per wave iteration
    const int w = t >> 6, lane = t & 63;
    {
        float b1v0 = b1[lane], b1v1 = b1[lane + 64];
        for (int i = 0; i < 8; i++) {
            int r = w * 8 + i;
            float s0 = b1v0, s1 = b1v1;
            const float* hr = &h_lds[r * FIN];
            #pragma unroll
            for (int k = 0; k < FIN; k++) {
                float hv = hr[k];
                s0 += hv * W1_lds[lane * 11 + k];
                s1 += hv * W1_lds[(lane + 64) * 11 + k];
            }
            float sm = s0 + s1, sq = s0 * s0 + s1 * s1;
            #pragma unroll
            for (int m = 1; m <= 32; m <<= 1) { sm += __shfl_xor(sm, m); sq += __shfl_xor(sq, m); }
            float mean = sm * (1.f / D);
            float var  = sq * (1.f / D) - mean * mean;
            float rs = rsqrtf(var + 1e-5f);
            xep_lds[r * 136 + lane]      = f2b(lrelu((s0 - mean) * rs));
            xep_lds[r * 136 + lane + 64] = f2b(lrelu((s1 - mean) * rs));
        }
    }
    __syncthreads();

    // phase 2: MFMA  Wh[32][128] = x @ Wg^T
    const int l15 = lane & 15, q = lane >> 4;
    const int mw = w & 1, np = w >> 1;
    f32x4 acc[4];
    #pragma unroll
    for (int nt = 0; nt < 4; nt++)
        #pragma unroll
        for (int r = 0; r < 4; r++) acc[nt][r] = 0.f;

    #pragma unroll
    for (int ks = 0; ks < 4; ks++) {
        bf8 av = *(const bf8*)&xep_lds[(mw * 16 + l15) * 136 + ks * 32 + q * 8];
        #pragma unroll
        for (int nt = 0; nt < 4; nt++) {
            bf8 bv = *(const bf8*)&wg_lds[((np * 4 + nt) * 16 + l15) * 136 + ks * 32 + q * 8];
            acc[nt] = __builtin_amdgcn_mfma_f32_16x16x32_bf16(av, bv, acc[nt], 0, 0, 0);
        }
    }

    // epilogue: +bg, e1/e2 partials
    float e1p[4] = {0.f, 0.f, 0.f, 0.f}, e2p[4] = {0.f, 0.f, 0.f, 0.f};
    #pragma unroll
    for (int nt = 0; nt < 4; nt++) {
        int col = (np * 4 + nt) * 16 + l15;
        float bgv = bg[col], a1v = a1[col], a2v = a2[col];
        #pragma unroll
        for (int r = 0; r < 4; r++) {
            float v = acc[nt][r] + bgv;
            acc[nt][r] = v;
            e1p[r] += v * a1v;
            e2p[r] += v * a2v;
        }
    }
    #pragma unroll
    for (int m = 1; m <= 8; m <<= 1) {
        #pragma unroll
        for (int r = 0; r < 4; r++) { e1p[r] += __shfl_xor(e1p[r], m); e2p[r] += __shfl_xor(e2p[r], m); }
    }
    if (l15 == 0) {
        #pragma unroll
        for (int r = 0; r < 4; r++) {
            ep1[np][mw * 16 + q * 4 + r] = e1p[r];
            ep2[np][mw * 16 + q * 4 + r] = e2p[r];
        }
    }
    __syncthreads();
    if (t < BR) {
        e1g[r0 + t] = (ep1[0][t] + ep1[1][t]) * LOG2E;   // exp2-domain
        e2g[r0 + t] = (ep2[0][t] + ep2[1][t]) * LOG2E;
    }
    #pragma unroll
    for (int nt = 0; nt < 4; nt++) {
        int col = (np * 4 + nt) * 16 + l15;
        #pragma unroll
        for (int r = 0; r < 4; r++)
            xep_lds[col * 36 + mw * 16 + q * 4 + r] = f2b(acc[nt][r]);
    }
    __syncthreads();
    {
        const int col = t >> 1, jh = (t & 1) * 16;
        unsigned short* dst = WhT + ((size_t)(bb * D + col)) * N + jloc + jh;
        #pragma unroll
        for (int i2 = 0; i2 < 4; i2++)
            *(uint2*)(dst + i2 * 4) = *(const uint2*)&xep_lds[col * 36 + jh + i2 * 4];
    }
}

// ---------------------------------------------------------------------------
// k_attn: flash-style GAT attention, MFMA PV + ones-MFMA for l, register
// prefetch pipeline, exp2-domain p with perm-packed bf16.
// Block = 32 i-rows, 512 threads (8 waves). Grid = 512.
// Last block (device counter) computes final log_softmax.
// ---------------------------------------------------------------------------
__global__ __launch_bounds__(512) void k_attn(
    const int* __restrict__ adj, const unsigned short* __restrict__ WhT,
    const float* __restrict__ e1g, const float* __restrict__ e2g,
    unsigned* __restrict__ pooled, unsigned* __restrict__ cnt,
    const float* __restrict__ W2, const float* __restrict__ b2,
    float* __restrict__ out)
{
    __shared__ __align__(16) short pT[TI * 136];     // A-op: [i][k=j], pad 8
    __shared__ __align__(16) short whT[D * 136];     // B-op: [d][k=j], pad 8
    __shared__ float statsp[4][TI][2];
    __shared__ float maxb[2][D];
    __shared__ int finalflag;

    const int t = threadIdx.x;
    const int b = blockIdx.y;
    const int i0 = blockIdx.x * TI;

    const int w = t >> 6, lane = t & 63;
    const int l15 = lane & 15, q = lane >> 4;
    const int mw = w & 1;          // m-tile (0/1)
    const int np = w >> 1;         // n-quarter (0..3)

    // staging maps
    const int rg = t >> 5;                 // 0..15 -> rows {2rg, 2rg+1}
    const int jq = (t & 31) * 4;           // j offset within chunk
    const int dr = t >> 4;                 // 0..31 (whT rows per pass)
    const int j8 = t & 15;                 // 16B granule within chunk

    const float e1r0 = e1g[b * N + i0 + rg * 2];       // pre-scaled by log2e
    const float e1r1 = e1g[b * N + i0 + rg * 2 + 1];

    const unsigned short* WhTb = WhT + (size_t)b * D * N;
    const int* adjb = adj + ((size_t)b * N + i0) * N;

    f32x4 acc[2], accl;
    #pragma unroll
    for (int nt = 0; nt < 2; nt++)
        #pragma unroll
        for (int r = 0; r < 4; r++) acc[nt][r] = 0.f;
    #pragma unroll
    for (int r = 0; r < 4; r++) accl[r] = 0.f;

    bf8 ones;
    #pragma unroll
    for (int i = 0; i < 8; i++) ones[i] = (short)0x3F80;   // bf16(1.0)

    // prefetch chunk 0
    int4 a0 = *(const int4*)(adjb + (size_t)(rg * 2) * N + jq);
    int4 a1r = *(const int4*)(adjb + (size_t)(rg * 2 + 1) * N + jq);
    float4 e2r = *(const float4*)&e2g[b * N + jq];
    bf8 wr0 = *(const bf8*)(WhTb + (size_t)(0 * 32 + dr) * N + j8 * 8);
    bf8 wr1 = *(const bf8*)(WhTb + (size_t)(1 * 32 + dr) * N + j8 * 8);
    bf8 wr2 = *(const bf8*)(WhTb + (size_t)(2 * 32 + dr) * N + j8 * 8);
    bf8 wr3 = *(const bf8*)(WhTb + (size_t)(3 * 32 + dr) * N + j8 * 8);

    for (int jc = 0; jc < N / JC; jc++) {
        // phase A: compute p from prefetched regs, pack, store LDS
        {
            float s0 = e1r0 + e2r.x, s1 = e1r0 + e2r.y,
                  s2 = e1r0 + e2r.z, s3 = e1r0 + e2r.w;
            float p0 = a0.x ? fexp2(fmaxf(s0, ALPHA * s0)) : 0.f;
            float p1 = a0.y ? fexp2(fmaxf(s1, ALPHA * s1)) : 0.f;
            float p2 = a0.z ? fexp2(fmaxf(s2, ALPHA * s2)) : 0.f;
            float p3 = a0.w ? fexp2(fmaxf(s3, ALPHA * s3)) : 0.f;
            *(uint2*)&pT[(rg * 2) * 136 + jq] = make_uint2(pack2(p0, p1), pack2(p2, p3));

            s0 = e1r1 + e2r.x; s1 = e1r1 + e2r.y;
            s2 = e1r1 + e2r.z; s3 = e1r1 + e2r.w;
            p0 = a1r.x ? fexp2(fmaxf(s0, ALPHA * s0)) : 0.f;
            p1 = a1r.y ? fexp2(fmaxf(s1, ALPHA * s1)) : 0.f;
            p2 = a1r.z ? fexp2(fmaxf(s2, ALPHA * s2)) : 0.f;
            p3 = a1r.w ? fexp2(fmaxf(s3, ALPHA * s3)) : 0.f;
            *(uint2*)&pT[(rg * 2 + 1) * 136 + jq] = make_uint2(pack2(p0, p1), pack2(p2, p3));

            *(bf8*)&whT[(0 * 32 + dr) * 136 + j8 * 8] = wr0;
            *(bf8*)&whT[(1 * 32 + dr) * 136 + j8 * 8] = wr1;
            *(bf8*)&whT[(2 * 32 + dr) * 136 + j8 * 8] = wr2;
            *(bf8*)&whT[(3 * 32 + dr) * 136 + j8 * 8] = wr3;
        }
        __syncthreads();

        // issue next chunk's prefetch (hidden behind MFMA + barrier)
        if (jc < N / JC - 1) {
            const int j0n = (jc + 1) * JC;
            a0  = *(const int4*)(adjb + (size_t)(rg * 2) * N + j0n + jq);
            a1r = *(const int4*)(adjb + (size_t)(rg * 2 + 1) * N + j0n + jq);
            e2r = *(const float4*)&e2g[b * N + j0n + jq];
            wr0 = *(const bf8*)(WhTb + (size_t)(0 * 32 + dr) * N + j0n + j8 * 8);
            wr1 = *(const bf8*)(WhTb + (size_t)(1 * 32 + dr) * N + j0n + j8 * 8);
            wr2 = *(const bf8*)(WhTb + (size_t)(2 * 32 + dr) * N + j0n + j8 * 8);
            wr3 = *(const bf8*)(WhTb + (size_t)(3 * 32 + dr) * N + j0n + j8 * 8);
        }

        // MFMA: O[32][128] += P @ WhT^T ; l += P @ ones
        #pragma unroll
        for (int ks = 0; ks < 4; ks++) {
            bf8 av = *(const bf8*)&pT[(mw * 16 + l15) * 136 + ks * 32 + q * 8];
            #pragma unroll
            for (int nt = 0; nt < 2; nt++) {
                bf8 bv = *(const bf8*)&whT[((np * 2 + nt) * 16 + l15) * 136 + ks * 32 + q * 8];
                acc[nt] = __builtin_amdgcn_mfma_f32_16x16x32_bf16(av, bv, acc[nt], 0, 0, 0);
            }
            accl = __builtin_amdgcn_mfma_f32_16x16x32_bf16(av, ones, accl, 0, 0, 0);
        }
        __syncthreads();
    }

    // epilogue: /l -> LN stats (cross-np via LDS) -> lrelu -> max-pool
    float smr[4] = {0.f, 0.f, 0.f, 0.f}, sqr[4] = {0.f, 0.f, 0.f, 0.f};
    #pragma unroll
    for (int r = 0; r < 4; r++) {
        float rinv = 1.f / accl[r];
        #pragma unroll
        for (int nt = 0; nt < 2; nt++) {
            float v = acc[nt][r] * rinv;
            acc[nt][r] = v;
            smr[r] += v;
            sqr[r] += v * v;
        }
    }
    #pragma unroll
    for (int m = 1; m <= 8; m <<= 1) {
        #pragma unroll
        for (int r = 0; r < 4; r++) { smr[r] += __shfl_xor(smr[r], m); sqr[r] += __shfl_xor(sqr[r], m); }
    }
    if (l15 == 0) {
        #pragma unroll
        for (int r = 0; r < 4; r++) {
            statsp[np][mw * 16 + q * 4 + r][0] = smr[r];
            statsp[np][mw * 16 + q * 4 + r][1] = sqr[r];
        }
    }
    __syncthreads();

    float mx[2] = {-1e30f, -1e30f};
    #pragma unroll
    for (int r = 0; r < 4; r++) {
        int row = mw * 16 + q * 4 + r;
        float s0 = statsp[0][row][0] + statsp[1][row][0] + statsp[2][row][0] + statsp[3][row][0];
        float s1 = statsp[0][row][1] + statsp[1][row][1] + statsp[2][row][1] + statsp[3][row][1];
        float mean = s0 * (1.f / D);
        float var  = s1 * (1.f / D) - mean * mean;
        float rs = rsqrtf(var + 1e-5f);
        #pragma unroll
        for (int nt = 0; nt < 2; nt++) {
            float v = lrelu((acc[nt][r] - mean) * rs);
            mx[nt] = fmaxf(mx[nt], v);
        }
    }
    #pragma unroll
    for (int m = 16; m <= 32; m <<= 1) {
        #pragma unroll
        for (int nt = 0; nt < 2; nt++) mx[nt] = fmaxf(mx[nt], __shfl_xor(mx[nt], m));
    }
    if (q == 0) {
        #pragma unroll
        for (int nt = 0; nt < 2; nt++) maxb[mw][(np * 2 + nt) * 16 + l15] = mx[nt];
    }
    __syncthreads();
    if (t < D) {
        float v = fmaxf(maxb[0][t], maxb[1][t]);
        atomicMax(&pooled[b * D + t], enc_key(v));
    }
    __syncthreads();           // all this block's atomics issued

    // completion counter; last block does final 128->2 matmul + log_softmax
    if (t == 0) {
        __threadfence();
        unsigned old = atomicAdd(cnt, 1u);
        finalflag = (old == NBLK_ATTN - 1) ? 1 : 0;
    }
    __syncthreads();
    if (finalflag && t < 256) {
        const int fb = t >> 5;
        const int fq = t & 31;
        float s0 = 0.f, s1 = 0.f;
        #pragma unroll
        for (int m = 0; m < 4; m++) {
            int dd = fq + 32 * m;
            unsigned key = __hip_atomic_load(&pooled[fb * D + dd], __ATOMIC_RELAXED,
                                             __HIP_MEMORY_SCOPE_AGENT);
            float v = dec_key(key);
            s0 += v * W2[dd];
            s1 += v * W2[D + dd];
        }
        #pragma unroll
        for (int m = 1; m <= 16; m <<= 1) { s0 += __shfl_xor(s0, m); s1 += __shfl_xor(s1, m); }
        if (fq == 0) {
            float o0 = s0 + b2[0], o1 = s1 + b2[1];
            float mxv = fmaxf(o0, o1);
            float ls = logf(__expf(o0 - mxv) + __expf(o1 - mxv));
            out[fb * 2 + 0] = o0 - mxv - ls;
            out[fb * 2 + 1] = o1 - mxv - ls;
        }
    }
}

extern "C" void kernel_launch(void* const* d_in, const int* in_sizes, int n_in,
                              void* d_out, int out_size, void* d_ws, size_t ws_size,
                              hipStream_t stream) {
    const float* h   = (const float*)d_in[0];
    const int*   adj = (const int*)d_in[1];
    const float* W1  = (const float*)d_in[2];
    const float* b1  = (const float*)d_in[3];
    const float* Wg  = (const float*)d_in[4];
    const float* bg  = (const float*)d_in[5];
    const float* a1  = (const float*)d_in[6];
    const float* a2  = (const float*)d_in[7];
    const float* W2  = (const float*)d_in[8];
    const float* b2  = (const float*)d_in[9];
    float* out = (float*)d_out;

    unsigned short* WhT = (unsigned short*)d_ws;                       // B*D*N bf16
    float* e1g = (float*)((char*)d_ws + (size_t)B * D * N * 2);        // B*N f32
    float* e2g = e1g + (size_t)B * N;                                  // B*N f32
    unsigned* pooled = (unsigned*)(e2g + (size_t)B * N);               // B*D u32
    unsigned* cnt = pooled + (size_t)B * D;                            // 1 u32
    unsigned short* Wgb = (unsigned short*)(cnt + 4);                  // D*D bf16

    k_prep<<<16, 256, 0, stream>>>(Wg, Wgb, pooled, cnt);
    k_proj<<<(B * N) / BR, 256, 0, stream>>>(h, W1, b1, Wgb, bg, a1, a2,
                                             WhT, e1g, e2g);
    k_attn<<<dim3(N / TI, B), 512, 0, stream>>>(adj, WhT, e1g, e2g, pooled, cnt,
                                                W2, b2, out);
}